// Round 14
// baseline (270.215 us; speedup 1.0000x reference)
//
#include <hip/hip_runtime.h>
#include <hip/hip_bf16.h>
#include <cfloat>

#define NN 50000
#define NE 1600000
#define NEG 0.2f
#define NBKT 782        // buckets of 64 nodes (bucket = dst>>6)
#define BNODE 64        // nodes per bucket
#define P1_TILE 2048    // edges per bin block (8 per thread, in registers)
#define P1_BLOCKS 782   // ceil(NE/P1_TILE)
#define BCAP 2560       // global slots per bucket (mean 2046, +11 sigma)
#define SLOTS 96        // ELL pad (deg ~ Poisson(32))
#define L2E 1.4426950408889634f

typedef __attribute__((ext_vector_type(8))) short bf8_t;   // 8 bf16 (4 VGPR)
typedef __attribute__((ext_vector_type(4))) float f4_t;

__device__ __forceinline__ float bf16bits_to_f(unsigned v) {
  return __uint_as_float(v << 16);
}
__device__ __forceinline__ unsigned f_to_bf16bits(float f) {
  unsigned u = __float_as_uint(f);
  return (u + 0x7fffu + ((u >> 16) & 1u)) >> 16;  // round-nearest-even
}

// ---- K1 phase 1: register-held edges; LDS = histogram + cursors only (6 KB
// -> 32 waves/CU). Pass 1: LDS histogram. Reserve: 1 global atomic/bucket.
// Pass 2: direct scatter to gbuf (L2 coalesces per-line bursts).
__global__ __launch_bounds__(256) void bin_kernel(
    const int* __restrict__ src, const int* __restrict__ dst,
    const float* __restrict__ ea, int* __restrict__ gcnt,
    int2* __restrict__ gbuf) {
  __shared__ int lcnt[NBKT];
  __shared__ int lcur[NBKT];
  int t = threadIdx.x;
  for (int i = t; i < NBKT; i += 256) lcnt[i] = 0;
  __syncthreads();
  int e0 = blockIdx.x * P1_TILE;
  int bb[8], vx[8], vy[8];
#pragma unroll
  for (int k = 0; k < 8; ++k) {
    int e = e0 + k * 256 + t;
    if (e < NE) {
      int d = dst[e];
      bb[k] = d >> 6;
      vx[k] = ((d & 63) << 16) | src[e];
      vy[k] = __float_as_int(ea[e]);
      atomicAdd(&lcnt[bb[k]], 1);
    } else {
      bb[k] = -1;
    }
  }
  __syncthreads();
  for (int i = t; i < NBKT; i += 256) lcur[i] = atomicAdd(&gcnt[i], lcnt[i]);
  __syncthreads();
#pragma unroll
  for (int k = 0; k < 8; ++k) {
    if (bb[k] >= 0) {
      int pos = atomicAdd(&lcur[bb[k]], 1);
      if (pos < BCAP) gbuf[(size_t)bb[k] * BCAP + pos] = make_int2(vx[k], vy[k]);
    }
  }
}

// ---- K1 phase 2: one block per bucket (782 = 3/CU) -> ELL csr + cnt ----
__global__ __launch_bounds__(256) void build_kernel(
    const int* __restrict__ gcnt, const int2* __restrict__ gbuf,
    int* __restrict__ cnt, unsigned* __restrict__ csr) {
  __shared__ int lc[BNODE];
  int t = threadIdx.x;
  int b = blockIdx.x;
  if (t < BNODE) lc[t] = 0;
  __syncthreads();
  int len = gcnt[b]; if (len > BCAP) len = BCAP;
  const int2* buf = gbuf + (size_t)b * BCAP;
  for (int i = t; i < len; i += 256) {
    int2 v = buf[i];
    int dl = (v.x >> 16) & 63;
    int s = v.x & 0xffff;
    int pos = atomicAdd(&lc[dl], 1);
    if (pos < SLOTS) {
      unsigned eb = ((unsigned)v.y) & 0xffff0000u;
      csr[(size_t)(b * BNODE + dl) * SLOTS + pos] = eb | (unsigned)s;
    }
  }
  __syncthreads();
  if (t < BNODE) {
    int n = b * BNODE + t;
    if (n < NN) cnt[n] = min(lc[t], SLOTS);
  }
}

__device__ __forceinline__ bf8_t pack8(const float* p) {
  bf8_t r;
#pragma unroll
  for (int i = 0; i < 8; ++i) r[i] = (short)f_to_bf16bits(p[i]);
  return r;
}

// ---- K2: MFMA GEMM + fused att dots (r13 version; measured-good) ----
template <bool FP32IN>
__global__ __launch_bounds__(256) void gemm_mfma_kernel(
    const void* __restrict__ xin, const float* __restrict__ W,
    const float* __restrict__ att_s, const float* __restrict__ att_d,
    unsigned short* __restrict__ xsb, float* __restrict__ a_src,
    float* __restrict__ a_dst) {
  __shared__ unsigned short Wt[64][68];  // Wt[n][k] bf16, padded
  int t = threadIdx.x;
  for (int i = t; i < 4096; i += 256) {
    int k = i >> 6, n = i & 63;
    Wt[n][k] = (unsigned short)f_to_bf16bits(W[i]);  // W row-major [k][n]
  }
  __syncthreads();
  int lane = t & 63, wave = t >> 6;
  int quad = lane >> 4, n16 = lane & 15;

  bf8_t bfrag[4][2];
#pragma unroll
  for (int nt = 0; nt < 4; ++nt)
#pragma unroll
    for (int kk = 0; kk < 2; ++kk)
      bfrag[nt][kk] = *(const bf8_t*)&Wt[nt * 16 + n16][kk * 32 + quad * 8];

  float as4[4], ad4[4];
#pragma unroll
  for (int nt = 0; nt < 4; ++nt) {
    as4[nt] = att_s[nt * 16 + n16];
    ad4[nt] = att_d[nt * 16 + n16];
  }

  int r0w = blockIdx.x * 128 + wave * 32;
#pragma unroll
  for (int tile = 0; tile < 2; ++tile) {
    int r0 = r0w + tile * 16;
    int rowA = r0 + n16; if (rowA > NN - 1) rowA = NN - 1;
    bf8_t af0, af1;
    if (FP32IN) {
      const float* xr = (const float*)xin + (size_t)rowA * 64 + quad * 8;
      af0 = pack8(xr);
      af1 = pack8(xr + 32);
    } else {
      const bf8_t* xrow =
          (const bf8_t*)((const unsigned short*)xin + (size_t)rowA * 64);
      af0 = xrow[quad];
      af1 = xrow[4 + quad];
    }
#pragma unroll
    for (int nt = 0; nt < 4; ++nt) {
      f4_t acc = {0.f, 0.f, 0.f, 0.f};
      acc = __builtin_amdgcn_mfma_f32_16x16x32_bf16(af0, bfrag[nt][0], acc, 0, 0, 0);
      acc = __builtin_amdgcn_mfma_f32_16x16x32_bf16(af1, bfrag[nt][1], acc, 0, 0, 0);
#pragma unroll
      for (int reg = 0; reg < 4; ++reg) {
        int row = r0 + quad * 4 + reg;
        float v = acc[reg];
        if (row < NN)
          xsb[(size_t)row * 64 + nt * 16 + n16] = (unsigned short)f_to_bf16bits(v);
        float p = v * as4[nt];
        float q = v * ad4[nt];
#pragma unroll
        for (int off = 8; off; off >>= 1) {
          p += __shfl_xor(p, off, 16);
          q += __shfl_xor(q, off, 16);
        }
        if (n16 == 0 && row < NN) {
          a_src[row * 4 + nt] = p * L2E;  // log2e folded
          a_dst[row * 4 + nt] = q * L2E;
        }
      }
    }
  }
}

// ---- K3: one wave per node (r13 version; measured-good) ----
template <bool HEAD>
__global__ __launch_bounds__(256) void aggregate_kernel(
    const int* __restrict__ cnt, const unsigned* __restrict__ csr,
    const unsigned short* __restrict__ xsb, const float* __restrict__ a_src,
    const float* __restrict__ a_dst, const float* __restrict__ We,
    const float* __restrict__ att_e, const float* __restrict__ bias,
    const float* __restrict__ res, const float* __restrict__ g,
    const float* __restrict__ beta, const float* __restrict__ Wout,
    const float* __restrict__ bout, float* __restrict__ out,
    unsigned short* __restrict__ out_b) {
  __shared__ __align__(16) uint2 rec[4][64][4];  // [wave][slot][head]
  int t = threadIdx.x;
  int lane = t & 63, wave = t >> 6;
  int n = blockIdx.x * 4 + wave;  // grid exact: 12500*4 == 50000
  int d2 = lane & 31;
  int hb = d2 >> 3;
  int half = lane >> 5;

  float sp = We[lane] * att_e[lane];
#pragma unroll
  for (int off = 8; off; off >>= 1) sp += __shfl_xor(sp, off, 16);
  sp *= L2E;
  float s0 = __shfl(sp, 0, 64), s1 = __shfl(sp, 16, 64);
  float s2 = __shfl(sp, 32, 64), s3 = __shfl(sp, 48, 64);

  const float4 adv = *(const float4*)(a_dst + (size_t)n * 4);

  int dn = cnt[n];
  int r0 = n * SLOTS, r1 = r0 + dn;
  float accx = 0.f, accy = 0.f, den = 0.f, easum = 0.f;
  const uint2* rpb = &rec[wave][half][hb];
  const char* xd = (const char*)xsb + d2 * 4;

  for (int base = r0; base < r1; base += 64) {
    int c = r1 - base; if (c > 64) c = 64;
    int e = base + lane;
    unsigned ce = (e < r1) ? csr[e] : 0u;
    float ea = __uint_as_float(ce & 0xffff0000u);
    easum += ea;
    unsigned soff = (ce & 0xffffu) * 128u;
    float ex0 = 0.f, ex1 = 0.f, ex2 = 0.f, ex3 = 0.f;
    if (e < r1) {
      const float4 av = *(const float4*)(a_src + (size_t)(ce & 0xffffu) * 4);
      float a0 = av.x + fmaf(ea, s0, adv.x); a0 = fmaxf(a0, NEG * a0);
      float a1 = av.y + fmaf(ea, s1, adv.y); a1 = fmaxf(a1, NEG * a1);
      float a2 = av.z + fmaf(ea, s2, adv.z); a2 = fmaxf(a2, NEG * a2);
      float a3 = av.w + fmaf(ea, s3, adv.w); a3 = fmaxf(a3, NEG * a3);
      ex0 = exp2f(a0); ex1 = exp2f(a1); ex2 = exp2f(a2); ex3 = exp2f(a3);
    }
    uint4* wp = (uint4*)&rec[wave][lane][0];
    wp[0] = make_uint4(soff, __float_as_uint(ex0), soff, __float_as_uint(ex1));
    wp[1] = make_uint4(soff, __float_as_uint(ex2), soff, __float_as_uint(ex3));
    // phase B: 8 slots (8 edges) per step; pad slots have ex=0 -> no-op
    int c8 = (c + 7) & ~7;
    for (int j = 0; j < c8; j += 8) {
      uint2 va = rpb[j * 4];       // slot j+half
      uint2 vb = rpb[j * 4 + 8];   // slot j+2+half
      uint2 vc = rpb[j * 4 + 16];  // slot j+4+half
      uint2 vd = rpb[j * 4 + 24];  // slot j+6+half
      unsigned ua = *(const unsigned*)(xd + va.x);
      unsigned ub = *(const unsigned*)(xd + vb.x);
      unsigned uc = *(const unsigned*)(xd + vc.x);
      unsigned ud = *(const unsigned*)(xd + vd.x);
      float efa = __uint_as_float(va.y), efb = __uint_as_float(vb.y);
      float efc = __uint_as_float(vc.y), efd = __uint_as_float(vd.y);
      den += (efa + efb) + (efc + efd);
      accx = fmaf(efa, __uint_as_float(ua << 16), accx);
      accy = fmaf(efa, __uint_as_float(ua & 0xffff0000u), accy);
      accx = fmaf(efb, __uint_as_float(ub << 16), accx);
      accy = fmaf(efb, __uint_as_float(ub & 0xffff0000u), accy);
      accx = fmaf(efc, __uint_as_float(uc << 16), accx);
      accy = fmaf(efc, __uint_as_float(uc & 0xffff0000u), accy);
      accx = fmaf(efd, __uint_as_float(ud << 16), accx);
      accy = fmaf(efd, __uint_as_float(ud & 0xffff0000u), accy);
    }
  }

  den += __shfl_xor(den, 32, 64);
  accx += __shfl_xor(accx, 32, 64);
  accy += __shfl_xor(accy, 32, 64);
#pragma unroll
  for (int off = 32; off; off >>= 1) easum += __shfl_xor(easum, off, 64);

  float loop_ea = easum / fmaxf((float)dn, 1.0f);
  float as_h = a_src[(size_t)n * 4 + hb];
  float adn = (hb == 0) ? adv.x : (hb == 1) ? adv.y : (hb == 2) ? adv.z : adv.w;
  float sph = (hb == 0) ? s0 : (hb == 1) ? s1 : (hb == 2) ? s2 : s3;
  float a_self = as_h + fmaf(loop_ea, sph, adn);
  a_self = fmaxf(a_self, NEG * a_self);
  float ex_self = exp2f(a_self);
  den += ex_self;
  unsigned un = *(const unsigned*)((const char*)xsb + (size_t)n * 128 + d2 * 4);
  accx = fmaf(ex_self, __uint_as_float(un << 16), accx);
  accy = fmaf(ex_self, __uint_as_float(un & 0xffff0000u), accy);

  float rden = 1.f / (den + 1e-16f);
  const float2 bi = *(const float2*)(bias + d2 * 2);
  const float2 rsd = *(const float2*)(res + (size_t)n * 64 + d2 * 2);
  float vx = accx * rden + bi.x + rsd.x;
  float vy = accy * rden + bi.y + rsd.y;
  float s = vx + vy;
#pragma unroll
  for (int off = 32; off; off >>= 1) s += __shfl_xor(s, off, 64);
  float mu = s * (1.0f / 128.0f);
  float dx = vx - mu, dy = vy - mu;
  float var = dx * dx + dy * dy;
#pragma unroll
  for (int off = 32; off; off >>= 1) var += __shfl_xor(var, off, 64);
  var *= (1.0f / 128.0f);
  float rstd = rsqrtf(var + 1e-5f);
  const float2 gg = *(const float2*)(g + d2 * 2);
  const float2 bb = *(const float2*)(beta + d2 * 2);
  float yx = dx * rstd * gg.x + bb.x;
  float yy = dy * rstd * gg.y + bb.y;
  yx = yx > 0.f ? yx : expm1f(yx);
  yy = yy > 0.f ? yy : expm1f(yy);
  if (HEAD) {
    const float2 wv = *(const float2*)(Wout + d2 * 2);
    float p = yx * wv.x + yy * wv.y;
#pragma unroll
    for (int off = 32; off; off >>= 1) p += __shfl_xor(p, off, 64);
    if (lane == 0) out[n] = p * 0.5f + bout[0];
  } else if (lane < 32) {
    *(float2*)(out + (size_t)n * 64 + d2 * 2) = make_float2(yx, yy);
    unsigned ob = f_to_bf16bits(yx) | (f_to_bf16bits(yy) << 16);
    *(unsigned*)(out_b + (size_t)n * 64 + d2 * 2) = ob;
  }
}

extern "C" void kernel_launch(void* const* d_in, const int* in_sizes, int n_in,
                              void* d_out, int out_size, void* d_ws,
                              size_t ws_size, hipStream_t stream) {
  const float* node_features = (const float*)d_in[0];
  const int* edge_index = (const int*)d_in[1];
  const int* src = edge_index;
  const int* dst = edge_index + NE;
  const float* edge_attr = (const float*)d_in[3];
  const float* W1 = (const float*)d_in[4];
  const float* att_src1 = (const float*)d_in[5];
  const float* att_dst1 = (const float*)d_in[6];
  const float* We1 = (const float*)d_in[7];
  const float* att_e1 = (const float*)d_in[8];
  const float* b1 = (const float*)d_in[9];
  const float* W2 = (const float*)d_in[10];
  const float* att_src2 = (const float*)d_in[11];
  const float* att_dst2 = (const float*)d_in[12];
  const float* We2 = (const float*)d_in[13];
  const float* att_e2 = (const float*)d_in[14];
  const float* b2 = (const float*)d_in[15];
  const float* g1 = (const float*)d_in[16];
  const float* beta1 = (const float*)d_in[17];
  const float* g2 = (const float*)d_in[18];
  const float* beta2 = (const float*)d_in[19];
  const float* Wout = (const float*)d_in[20];
  const float* bout = (const float*)d_in[21];
  float* out = (float*)d_out;

  char* ws = (char*)d_ws;
  size_t o = 0;
  auto alloc = [&](size_t bytes) {
    void* p = ws + o;
    o += (bytes + 255) & ~(size_t)255;
    return p;
  };
  int* gcnt = (int*)alloc((size_t)NBKT * 4);
  int2* gbuf = (int2*)alloc((size_t)NBKT * BCAP * 8);
  int* cnt = (int*)alloc((size_t)NN * 4);
  unsigned* csr = (unsigned*)alloc((size_t)NN * SLOTS * 4);
  unsigned short* xsb = (unsigned short*)alloc((size_t)NN * 64 * 2);
  unsigned short* h1b = (unsigned short*)alloc((size_t)NN * 64 * 2);
  float* a_srcb = (float*)alloc((size_t)NN * 4 * 4);
  float* a_dstb = (float*)alloc((size_t)NN * 4 * 4);
  float* h1 = (float*)alloc((size_t)NN * 64 * 4);

  hipMemsetAsync(gcnt, 0, (size_t)NBKT * 4, stream);

  // bucketed CSR build
  bin_kernel<<<P1_BLOCKS, 256, 0, stream>>>(src, dst, edge_attr, gcnt, gbuf);
  build_kernel<<<NBKT, 256, 0, stream>>>(gcnt, gbuf, cnt, csr);

  // layer 1 (fp32 input path packs bf16 A-fragments in-register)
  gemm_mfma_kernel<true><<<391, 256, 0, stream>>>(
      node_features, W1, att_src1, att_dst1, xsb, a_srcb, a_dstb);
  aggregate_kernel<false><<<NN / 4, 256, 0, stream>>>(
      cnt, csr, xsb, a_srcb, a_dstb, We1, att_e1, b1, node_features, g1, beta1,
      nullptr, nullptr, h1, h1b);

  // layer 2
  gemm_mfma_kernel<false><<<391, 256, 0, stream>>>(
      h1b, W2, att_src2, att_dst2, xsb, a_srcb, a_dstb);
  aggregate_kernel<true><<<NN / 4, 256, 0, stream>>>(
      cnt, csr, xsb, a_srcb, a_dstb, We2, att_e2, b2, h1, g2, beta2, Wout, bout,
      out, nullptr);
}

// Round 15
// 266.554 us; speedup vs baseline: 1.0137x; 1.0137x over previous
//
#include <hip/hip_runtime.h>
#include <hip/hip_bf16.h>
#include <cfloat>

#define NN 50000
#define NE 1600000
#define NEG 0.2f
#define NBKT 1563       // buckets of 32 nodes (bucket = dst>>5)
#define BNODE 32        // nodes per bucket
#define P1_TILE 2048    // edges per bin block (8 per thread, in registers)
#define P1_BLOCKS 782   // ceil(NE/P1_TILE)
#define BCAP 1280       // global slots per bucket (mean 1024, +8 sigma)
#define SLOTS 96        // ELL pad (deg ~ Poisson(32))
#define L2E 1.4426950408889634f

typedef __attribute__((ext_vector_type(8))) short bf8_t;   // 8 bf16 (4 VGPR)
typedef __attribute__((ext_vector_type(4))) float f4_t;

__device__ __forceinline__ float bf16bits_to_f(unsigned v) {
  return __uint_as_float(v << 16);
}
__device__ __forceinline__ unsigned f_to_bf16bits(float f) {
  unsigned u = __float_as_uint(f);
  return (u + 0x7fffu + ((u >> 16) & 1u)) >> 16;  // round-nearest-even
}

// ---- K0: build extended weights W' = [W | L2E*w_s | L2E*w_d | pad] (bf16)
// w_s[k,h] = sum_c W[k][h*16+c]*att_s[h*16+c]  (att dots become GEMM columns)
// 2 blocks: blockIdx 0 -> layer 1, 1 -> layer 2.
__global__ __launch_bounds__(256) void prep_kernel(
    const float* __restrict__ W1, const float* __restrict__ as1,
    const float* __restrict__ ad1, unsigned short* __restrict__ We1,
    const float* __restrict__ W2, const float* __restrict__ as2,
    const float* __restrict__ ad2, unsigned short* __restrict__ We2) {
  const float* W = blockIdx.x ? W2 : W1;
  const float* as = blockIdx.x ? as2 : as1;
  const float* ad = blockIdx.x ? ad2 : ad1;
  unsigned short* Wx = blockIdx.x ? We2 : We1;
  int t = threadIdx.x;
  if (t < 64) {  // k = t
    const float* wr = W + t * 64;
#pragma unroll
    for (int h = 0; h < 4; ++h) {
      float ps = 0.f, pd = 0.f;
#pragma unroll
      for (int c = 0; c < 16; ++c) {
        ps = fmaf(wr[h * 16 + c], as[h * 16 + c], ps);
        pd = fmaf(wr[h * 16 + c], ad[h * 16 + c], pd);
      }
      Wx[t * 80 + 64 + h] = (unsigned short)f_to_bf16bits(ps * L2E);
      Wx[t * 80 + 68 + h] = (unsigned short)f_to_bf16bits(pd * L2E);
    }
#pragma unroll
    for (int j = 72; j < 80; ++j) Wx[t * 80 + j] = 0;
  }
  for (int i = t; i < 4096; i += 256) {
    int k = i >> 6, n = i & 63;
    Wx[k * 80 + n] = (unsigned short)f_to_bf16bits(W[i]);
  }
}

// ---- K1 phase 1: register-held edges; LDS = histogram + cursors (12.5 KB).
__global__ __launch_bounds__(256) void bin_kernel(
    const int* __restrict__ src, const int* __restrict__ dst,
    const float* __restrict__ ea, int* __restrict__ gcnt,
    int2* __restrict__ gbuf) {
  __shared__ int lcnt[NBKT];
  __shared__ int lcur[NBKT];
  int t = threadIdx.x;
  for (int i = t; i < NBKT; i += 256) lcnt[i] = 0;
  __syncthreads();
  int e0 = blockIdx.x * P1_TILE;
  int bb[8], vx[8], vy[8];
#pragma unroll
  for (int k = 0; k < 8; ++k) {
    int e = e0 + k * 256 + t;
    if (e < NE) {
      int d = dst[e];
      bb[k] = d >> 5;
      vx[k] = ((d & 31) << 16) | src[e];
      vy[k] = __float_as_int(ea[e]);
      atomicAdd(&lcnt[bb[k]], 1);
    } else {
      bb[k] = -1;
    }
  }
  __syncthreads();
  for (int i = t; i < NBKT; i += 256) lcur[i] = atomicAdd(&gcnt[i], lcnt[i]);
  __syncthreads();
#pragma unroll
  for (int k = 0; k < 8; ++k) {
    if (bb[k] >= 0) {
      int pos = atomicAdd(&lcur[bb[k]], 1);
      if (pos < BCAP) gbuf[(size_t)bb[k] * BCAP + pos] = make_int2(vx[k], vy[k]);
    }
  }
}

// ---- K1 phase 2: one block per bucket (1563 = 6/CU) -> ELL csr + cnt ----
__global__ __launch_bounds__(256) void build_kernel(
    const int* __restrict__ gcnt, const int2* __restrict__ gbuf,
    int* __restrict__ cnt, unsigned* __restrict__ csr) {
  __shared__ int lc[BNODE];
  int t = threadIdx.x;
  int b = blockIdx.x;
  if (t < BNODE) lc[t] = 0;
  __syncthreads();
  int len = gcnt[b]; if (len > BCAP) len = BCAP;
  const int2* buf = gbuf + (size_t)b * BCAP;
  for (int i = t; i < len; i += 256) {
    int2 v = buf[i];
    int dl = (v.x >> 16) & 31;
    int s = v.x & 0xffff;
    int pos = atomicAdd(&lc[dl], 1);
    if (pos < SLOTS) {
      unsigned eb = ((unsigned)v.y) & 0xffff0000u;
      csr[(size_t)(b * BNODE + dl) * SLOTS + pos] = eb | (unsigned)s;
    }
  }
  __syncthreads();
  if (t < BNODE) {
    int n = b * BNODE + t;
    if (n < NN) cnt[n] = min(lc[t], SLOTS);
  }
}

__device__ __forceinline__ bf8_t pack8(const float* p) {
  bf8_t r;
#pragma unroll
  for (int i = 0; i < 8; ++i) r[i] = (short)f_to_bf16bits(p[i]);
  return r;
}

// ---- K2: MFMA GEMM with extended B (80 cols): nt 0..3 -> xsb, nt 4 ->
// a_src/a_dst directly from D-frags (no butterflies). 64 rows/block, grid 782.
template <bool FP32IN>
__global__ __launch_bounds__(256) void gemm_mfma_kernel(
    const void* __restrict__ xin, const unsigned short* __restrict__ Wext,
    unsigned short* __restrict__ xsb, float* __restrict__ a_src,
    float* __restrict__ a_dst) {
  __shared__ unsigned short Wt[80][68];  // Wt[n][k] bf16, padded
  int t = threadIdx.x;
  for (int i = t; i < 5120; i += 256) {
    int k = i / 80, n = i - k * 80;
    Wt[n][k] = Wext[i];  // Wext row-major [k][80]
  }
  __syncthreads();
  int lane = t & 63, wave = t >> 6;
  int quad = lane >> 4, n16 = lane & 15;

  bf8_t bfrag[5][2];
#pragma unroll
  for (int nt = 0; nt < 5; ++nt)
#pragma unroll
    for (int kk = 0; kk < 2; ++kk)
      bfrag[nt][kk] = *(const bf8_t*)&Wt[nt * 16 + n16][kk * 32 + quad * 8];

  int r0 = blockIdx.x * 64 + wave * 16;
  int rowA = r0 + n16; if (rowA > NN - 1) rowA = NN - 1;
  bf8_t af0, af1;
  if (FP32IN) {
    const float* xr = (const float*)xin + (size_t)rowA * 64 + quad * 8;
    af0 = pack8(xr);
    af1 = pack8(xr + 32);
  } else {
    const bf8_t* xrow =
        (const bf8_t*)((const unsigned short*)xin + (size_t)rowA * 64);
    af0 = xrow[quad];
    af1 = xrow[4 + quad];
  }
#pragma unroll
  for (int nt = 0; nt < 5; ++nt) {
    f4_t acc = {0.f, 0.f, 0.f, 0.f};
    acc = __builtin_amdgcn_mfma_f32_16x16x32_bf16(af0, bfrag[nt][0], acc, 0, 0, 0);
    acc = __builtin_amdgcn_mfma_f32_16x16x32_bf16(af1, bfrag[nt][1], acc, 0, 0, 0);
    if (nt < 4) {
#pragma unroll
      for (int reg = 0; reg < 4; ++reg) {
        int row = r0 + quad * 4 + reg;
        if (row < NN)
          xsb[(size_t)row * 64 + nt * 16 + n16] =
              (unsigned short)f_to_bf16bits(acc[reg]);
      }
    } else {
#pragma unroll
      for (int reg = 0; reg < 4; ++reg) {
        int row = r0 + quad * 4 + reg;
        if (row < NN && n16 < 8) {
          if (n16 < 4) a_src[row * 4 + n16] = acc[reg];
          else a_dst[row * 4 + (n16 - 4)] = acc[reg];
        }
      }
    }
  }
}

// ---- K3: one wave per node (r13 version; measured-good, untouched) ----
template <bool HEAD>
__global__ __launch_bounds__(256) void aggregate_kernel(
    const int* __restrict__ cnt, const unsigned* __restrict__ csr,
    const unsigned short* __restrict__ xsb, const float* __restrict__ a_src,
    const float* __restrict__ a_dst, const float* __restrict__ We,
    const float* __restrict__ att_e, const float* __restrict__ bias,
    const float* __restrict__ res, const float* __restrict__ g,
    const float* __restrict__ beta, const float* __restrict__ Wout,
    const float* __restrict__ bout, float* __restrict__ out,
    unsigned short* __restrict__ out_b) {
  __shared__ __align__(16) uint2 rec[4][64][4];  // [wave][slot][head]
  int t = threadIdx.x;
  int lane = t & 63, wave = t >> 6;
  int n = blockIdx.x * 4 + wave;  // grid exact: 12500*4 == 50000
  int d2 = lane & 31;
  int hb = d2 >> 3;
  int half = lane >> 5;

  float sp = We[lane] * att_e[lane];
#pragma unroll
  for (int off = 8; off; off >>= 1) sp += __shfl_xor(sp, off, 16);
  sp *= L2E;
  float s0 = __shfl(sp, 0, 64), s1 = __shfl(sp, 16, 64);
  float s2 = __shfl(sp, 32, 64), s3 = __shfl(sp, 48, 64);

  const float4 adv = *(const float4*)(a_dst + (size_t)n * 4);

  int dn = cnt[n];
  int r0 = n * SLOTS, r1 = r0 + dn;
  float accx = 0.f, accy = 0.f, den = 0.f, easum = 0.f;
  const uint2* rpb = &rec[wave][half][hb];
  const char* xd = (const char*)xsb + d2 * 4;

  for (int base = r0; base < r1; base += 64) {
    int c = r1 - base; if (c > 64) c = 64;
    int e = base + lane;
    unsigned ce = (e < r1) ? csr[e] : 0u;
    float ea = __uint_as_float(ce & 0xffff0000u);
    easum += ea;
    unsigned soff = (ce & 0xffffu) * 128u;
    float ex0 = 0.f, ex1 = 0.f, ex2 = 0.f, ex3 = 0.f;
    if (e < r1) {
      const float4 av = *(const float4*)(a_src + (size_t)(ce & 0xffffu) * 4);
      float a0 = av.x + fmaf(ea, s0, adv.x); a0 = fmaxf(a0, NEG * a0);
      float a1 = av.y + fmaf(ea, s1, adv.y); a1 = fmaxf(a1, NEG * a1);
      float a2 = av.z + fmaf(ea, s2, adv.z); a2 = fmaxf(a2, NEG * a2);
      float a3 = av.w + fmaf(ea, s3, adv.w); a3 = fmaxf(a3, NEG * a3);
      ex0 = exp2f(a0); ex1 = exp2f(a1); ex2 = exp2f(a2); ex3 = exp2f(a3);
    }
    uint4* wp = (uint4*)&rec[wave][lane][0];
    wp[0] = make_uint4(soff, __float_as_uint(ex0), soff, __float_as_uint(ex1));
    wp[1] = make_uint4(soff, __float_as_uint(ex2), soff, __float_as_uint(ex3));
    // phase B: 8 slots (8 edges) per step; pad slots have ex=0 -> no-op
    int c8 = (c + 7) & ~7;
    for (int j = 0; j < c8; j += 8) {
      uint2 va = rpb[j * 4];       // slot j+half
      uint2 vb = rpb[j * 4 + 8];   // slot j+2+half
      uint2 vc = rpb[j * 4 + 16];  // slot j+4+half
      uint2 vd = rpb[j * 4 + 24];  // slot j+6+half
      unsigned ua = *(const unsigned*)(xd + va.x);
      unsigned ub = *(const unsigned*)(xd + vb.x);
      unsigned uc = *(const unsigned*)(xd + vc.x);
      unsigned ud = *(const unsigned*)(xd + vd.x);
      float efa = __uint_as_float(va.y), efb = __uint_as_float(vb.y);
      float efc = __uint_as_float(vc.y), efd = __uint_as_float(vd.y);
      den += (efa + efb) + (efc + efd);
      accx = fmaf(efa, __uint_as_float(ua << 16), accx);
      accy = fmaf(efa, __uint_as_float(ua & 0xffff0000u), accy);
      accx = fmaf(efb, __uint_as_float(ub << 16), accx);
      accy = fmaf(efb, __uint_as_float(ub & 0xffff0000u), accy);
      accx = fmaf(efc, __uint_as_float(uc << 16), accx);
      accy = fmaf(efc, __uint_as_float(uc & 0xffff0000u), accy);
      accx = fmaf(efd, __uint_as_float(ud << 16), accx);
      accy = fmaf(efd, __uint_as_float(ud & 0xffff0000u), accy);
    }
  }

  den += __shfl_xor(den, 32, 64);
  accx += __shfl_xor(accx, 32, 64);
  accy += __shfl_xor(accy, 32, 64);
#pragma unroll
  for (int off = 32; off; off >>= 1) easum += __shfl_xor(easum, off, 64);

  float loop_ea = easum / fmaxf((float)dn, 1.0f);
  float as_h = a_src[(size_t)n * 4 + hb];
  float adn = (hb == 0) ? adv.x : (hb == 1) ? adv.y : (hb == 2) ? adv.z : adv.w;
  float sph = (hb == 0) ? s0 : (hb == 1) ? s1 : (hb == 2) ? s2 : s3;
  float a_self = as_h + fmaf(loop_ea, sph, adn);
  a_self = fmaxf(a_self, NEG * a_self);
  float ex_self = exp2f(a_self);
  den += ex_self;
  unsigned un = *(const unsigned*)((const char*)xsb + (size_t)n * 128 + d2 * 4);
  accx = fmaf(ex_self, __uint_as_float(un << 16), accx);
  accy = fmaf(ex_self, __uint_as_float(un & 0xffff0000u), accy);

  float rden = 1.f / (den + 1e-16f);
  const float2 bi = *(const float2*)(bias + d2 * 2);
  const float2 rsd = *(const float2*)(res + (size_t)n * 64 + d2 * 2);
  float vx = accx * rden + bi.x + rsd.x;
  float vy = accy * rden + bi.y + rsd.y;
  float s = vx + vy;
#pragma unroll
  for (int off = 32; off; off >>= 1) s += __shfl_xor(s, off, 64);
  float mu = s * (1.0f / 128.0f);
  float dx = vx - mu, dy = vy - mu;
  float var = dx * dx + dy * dy;
#pragma unroll
  for (int off = 32; off; off >>= 1) var += __shfl_xor(var, off, 64);
  var *= (1.0f / 128.0f);
  float rstd = rsqrtf(var + 1e-5f);
  const float2 gg = *(const float2*)(g + d2 * 2);
  const float2 bb = *(const float2*)(beta + d2 * 2);
  float yx = dx * rstd * gg.x + bb.x;
  float yy = dy * rstd * gg.y + bb.y;
  yx = yx > 0.f ? yx : expm1f(yx);
  yy = yy > 0.f ? yy : expm1f(yy);
  if (HEAD) {
    const float2 wv = *(const float2*)(Wout + d2 * 2);
    float p = yx * wv.x + yy * wv.y;
#pragma unroll
    for (int off = 32; off; off >>= 1) p += __shfl_xor(p, off, 64);
    if (lane == 0) out[n] = p * 0.5f + bout[0];
  } else if (lane < 32) {
    *(float2*)(out + (size_t)n * 64 + d2 * 2) = make_float2(yx, yy);
    unsigned ob = f_to_bf16bits(yx) | (f_to_bf16bits(yy) << 16);
    *(unsigned*)(out_b + (size_t)n * 64 + d2 * 2) = ob;
  }
}

extern "C" void kernel_launch(void* const* d_in, const int* in_sizes, int n_in,
                              void* d_out, int out_size, void* d_ws,
                              size_t ws_size, hipStream_t stream) {
  const float* node_features = (const float*)d_in[0];
  const int* edge_index = (const int*)d_in[1];
  const int* src = edge_index;
  const int* dst = edge_index + NE;
  const float* edge_attr = (const float*)d_in[3];
  const float* W1 = (const float*)d_in[4];
  const float* att_src1 = (const float*)d_in[5];
  const float* att_dst1 = (const float*)d_in[6];
  const float* We1 = (const float*)d_in[7];
  const float* att_e1 = (const float*)d_in[8];
  const float* b1 = (const float*)d_in[9];
  const float* W2 = (const float*)d_in[10];
  const float* att_src2 = (const float*)d_in[11];
  const float* att_dst2 = (const float*)d_in[12];
  const float* We2 = (const float*)d_in[13];
  const float* att_e2 = (const float*)d_in[14];
  const float* b2 = (const float*)d_in[15];
  const float* g1 = (const float*)d_in[16];
  const float* beta1 = (const float*)d_in[17];
  const float* g2 = (const float*)d_in[18];
  const float* beta2 = (const float*)d_in[19];
  const float* Wout = (const float*)d_in[20];
  const float* bout = (const float*)d_in[21];
  float* out = (float*)d_out;

  char* ws = (char*)d_ws;
  size_t o = 0;
  auto alloc = [&](size_t bytes) {
    void* p = ws + o;
    o += (bytes + 255) & ~(size_t)255;
    return p;
  };
  int* gcnt = (int*)alloc((size_t)NBKT * 4);
  int2* gbuf = (int2*)alloc((size_t)NBKT * BCAP * 8);
  int* cnt = (int*)alloc((size_t)NN * 4);
  unsigned* csr = (unsigned*)alloc((size_t)NN * SLOTS * 4);
  unsigned short* xsb = (unsigned short*)alloc((size_t)NN * 64 * 2);
  unsigned short* h1b = (unsigned short*)alloc((size_t)NN * 64 * 2);
  unsigned short* Wext1 = (unsigned short*)alloc(64 * 80 * 2);
  unsigned short* Wext2 = (unsigned short*)alloc(64 * 80 * 2);
  float* a_srcb = (float*)alloc((size_t)NN * 4 * 4);
  float* a_dstb = (float*)alloc((size_t)NN * 4 * 4);
  float* h1 = (float*)alloc((size_t)NN * 64 * 4);

  hipMemsetAsync(gcnt, 0, (size_t)NBKT * 4, stream);

  // extended weights (att dots folded as GEMM columns)
  prep_kernel<<<2, 256, 0, stream>>>(W1, att_src1, att_dst1, Wext1, W2,
                                     att_src2, att_dst2, Wext2);

  // bucketed CSR build
  bin_kernel<<<P1_BLOCKS, 256, 0, stream>>>(src, dst, edge_attr, gcnt, gbuf);
  build_kernel<<<NBKT, 256, 0, stream>>>(gcnt, gbuf, cnt, csr);

  // layer 1 (fp32 input path packs bf16 A-fragments in-register)
  gemm_mfma_kernel<true><<<782, 256, 0, stream>>>(node_features, Wext1, xsb,
                                                  a_srcb, a_dstb);
  aggregate_kernel<false><<<NN / 4, 256, 0, stream>>>(
      cnt, csr, xsb, a_srcb, a_dstb, We1, att_e1, b1, node_features, g1, beta1,
      nullptr, nullptr, h1, h1b);

  // layer 2
  gemm_mfma_kernel<false><<<782, 256, 0, stream>>>(h1b, Wext2, xsb, a_srcb,
                                                   a_dstb);
  aggregate_kernel<true><<<NN / 4, 256, 0, stream>>>(
      cnt, csr, xsb, a_srcb, a_dstb, We2, att_e2, b2, h1, g2, beta2, Wout, bout,
      out, nullptr);
}

// Round 16
// 255.369 us; speedup vs baseline: 1.0581x; 1.0438x over previous
//
#include <hip/hip_runtime.h>
#include <hip/hip_bf16.h>
#include <cfloat>

#define NN 50000
#define NE 1600000
#define NEG 0.2f
#define NBKT 1563       // buckets of 32 nodes (bucket = dst>>5)
#define BNODE 32        // nodes per bucket
#define P1_TILE 2048    // edges per bin block (8 per thread, in registers)
#define P1_BLOCKS 782   // ceil(NE/P1_TILE)
#define GEMM_BLOCKS 782 // 64 rows/block
#define BCAP 1280       // global slots per bucket (mean 1024, +8 sigma)
#define SLOTS 96        // ELL pad (deg ~ Poisson(32))
#define L2E 1.4426950408889634f
#define SMEM_BYTES 12512  // max(bin 2*1563*4=12504, gemm 80*68*2=10880)

typedef __attribute__((ext_vector_type(8))) short bf8_t;   // 8 bf16 (4 VGPR)
typedef __attribute__((ext_vector_type(4))) float f4_t;

__device__ __forceinline__ float bf16bits_to_f(unsigned v) {
  return __uint_as_float(v << 16);
}
__device__ __forceinline__ unsigned f_to_bf16bits(float f) {
  unsigned u = __float_as_uint(f);
  return (u + 0x7fffu + ((u >> 16) & 1u)) >> 16;  // round-nearest-even
}

__device__ __forceinline__ bf8_t pack8(const float* p) {
  bf8_t r;
#pragma unroll
  for (int i = 0; i < 8; ++i) r[i] = (short)f_to_bf16bits(p[i]);
  return r;
}

// ---- bin body: register-held edges; LDS = histogram + cursors ----
__device__ void bin_body(char* smem, int blk, const int* __restrict__ src,
                         const int* __restrict__ dst,
                         const float* __restrict__ ea, int* __restrict__ gcnt,
                         int2* __restrict__ gbuf) {
  int* lcnt = (int*)smem;
  int* lcur = lcnt + NBKT;
  int t = threadIdx.x;
  for (int i = t; i < NBKT; i += 256) lcnt[i] = 0;
  __syncthreads();
  int e0 = blk * P1_TILE;
  int bb[8], vx[8], vy[8];
#pragma unroll
  for (int k = 0; k < 8; ++k) {
    int e = e0 + k * 256 + t;
    if (e < NE) {
      int d = dst[e];
      bb[k] = d >> 5;
      vx[k] = ((d & 31) << 16) | src[e];
      vy[k] = __float_as_int(ea[e]);
      atomicAdd(&lcnt[bb[k]], 1);
    } else {
      bb[k] = -1;
    }
  }
  __syncthreads();
  for (int i = t; i < NBKT; i += 256) lcur[i] = atomicAdd(&gcnt[i], lcnt[i]);
  __syncthreads();
#pragma unroll
  for (int k = 0; k < 8; ++k) {
    if (bb[k] >= 0) {
      int pos = atomicAdd(&lcur[bb[k]], 1);
      if (pos < BCAP) gbuf[(size_t)bb[k] * BCAP + pos] = make_int2(vx[k], vy[k]);
    }
  }
}

// ---- gemm body: MFMA GEMM with self-built extended B (80 cols).
// Cols 0..63 = bf16(W); 64..67 = L2E*W@att_s per head; 68..71 = L2E*W@att_d;
// 72..79 = 0. nt 0..3 -> xsb; nt 4 -> a_src/a_dst from D-frags.
// Layouts (m89/m91 verified): A[m=lane&15][k=quad*8+j], B[k=quad*8+j][n=lane&15],
// D col=lane&15 row=quad*4+reg.
template <bool FP32IN>
__device__ void gemm_body(char* smem, int blk, const void* __restrict__ xin,
                          const float* __restrict__ W,
                          const float* __restrict__ att_s,
                          const float* __restrict__ att_d,
                          unsigned short* __restrict__ xsb,
                          float* __restrict__ a_src,
                          float* __restrict__ a_dst) {
  unsigned short(*Wt)[68] = (unsigned short(*)[68])smem;  // [80][68]
  int t = threadIdx.x;
  for (int i = t; i < 4096; i += 256) {
    int k = i >> 6, n = i & 63;
    Wt[n][k] = (unsigned short)f_to_bf16bits(W[i]);  // W row-major [k][n]
  }
  __syncthreads();
  {  // extended attention columns: t -> (k = t&63, h = t>>6)
    int k = t & 63, h = t >> 6;
    float ps = 0.f, pd = 0.f;
#pragma unroll
    for (int c = 0; c < 16; ++c) {
      float w = bf16bits_to_f(Wt[h * 16 + c][k]);
      ps = fmaf(w, att_s[h * 16 + c], ps);
      pd = fmaf(w, att_d[h * 16 + c], pd);
    }
    Wt[64 + h][k] = (unsigned short)f_to_bf16bits(ps * L2E);
    Wt[68 + h][k] = (unsigned short)f_to_bf16bits(pd * L2E);
    Wt[72 + h][k] = 0;
    Wt[76 + h][k] = 0;
  }
  __syncthreads();
  int lane = t & 63, wave = t >> 6;
  int quad = lane >> 4, n16 = lane & 15;

  bf8_t bfrag[5][2];
#pragma unroll
  for (int nt = 0; nt < 5; ++nt)
#pragma unroll
    for (int kk = 0; kk < 2; ++kk)
      bfrag[nt][kk] = *(const bf8_t*)&Wt[nt * 16 + n16][kk * 32 + quad * 8];

  int r0 = blk * 64 + wave * 16;
  int rowA = r0 + n16; if (rowA > NN - 1) rowA = NN - 1;
  bf8_t af0, af1;
  if (FP32IN) {
    const float* xr = (const float*)xin + (size_t)rowA * 64 + quad * 8;
    af0 = pack8(xr);
    af1 = pack8(xr + 32);
  } else {
    const bf8_t* xrow =
        (const bf8_t*)((const unsigned short*)xin + (size_t)rowA * 64);
    af0 = xrow[quad];
    af1 = xrow[4 + quad];
  }
#pragma unroll
  for (int nt = 0; nt < 5; ++nt) {
    f4_t acc = {0.f, 0.f, 0.f, 0.f};
    acc = __builtin_amdgcn_mfma_f32_16x16x32_bf16(af0, bfrag[nt][0], acc, 0, 0, 0);
    acc = __builtin_amdgcn_mfma_f32_16x16x32_bf16(af1, bfrag[nt][1], acc, 0, 0, 0);
    if (nt < 4) {
#pragma unroll
      for (int reg = 0; reg < 4; ++reg) {
        int row = r0 + quad * 4 + reg;
        if (row < NN)
          xsb[(size_t)row * 64 + nt * 16 + n16] =
              (unsigned short)f_to_bf16bits(acc[reg]);
      }
    } else {
#pragma unroll
      for (int reg = 0; reg < 4; ++reg) {
        int row = r0 + quad * 4 + reg;
        if (row < NN && n16 < 8) {
          if (n16 < 4) a_src[row * 4 + n16] = acc[reg];
          else a_dst[row * 4 + (n16 - 4)] = acc[reg];
        }
      }
    }
  }
}

// ---- K1: fused [bin | layer-1 GEMM] heterogeneous grid (independent work;
// r1-proven pattern). Blocks 0..781 bin, 782..1563 gemm1.
__global__ __launch_bounds__(256) void front_kernel(
    const int* __restrict__ src, const int* __restrict__ dst,
    const float* __restrict__ ea, int* __restrict__ gcnt,
    int2* __restrict__ gbuf, const float* __restrict__ x,
    const float* __restrict__ W1, const float* __restrict__ as1,
    const float* __restrict__ ad1, unsigned short* __restrict__ xsb,
    float* __restrict__ a_src, float* __restrict__ a_dst) {
  __shared__ __align__(16) char smem[SMEM_BYTES];
  if (blockIdx.x < P1_BLOCKS) {
    bin_body(smem, blockIdx.x, src, dst, ea, gcnt, gbuf);
  } else {
    gemm_body<true>(smem, blockIdx.x - P1_BLOCKS, x, W1, as1, ad1, xsb, a_src,
                    a_dst);
  }
}

// ---- K2: layer-2 GEMM standalone ----
__global__ __launch_bounds__(256) void gemm2_kernel(
    const unsigned short* __restrict__ xin, const float* __restrict__ W,
    const float* __restrict__ att_s, const float* __restrict__ att_d,
    unsigned short* __restrict__ xsb, float* __restrict__ a_src,
    float* __restrict__ a_dst) {
  __shared__ __align__(16) char smem[SMEM_BYTES];
  gemm_body<false>(smem, blockIdx.x, xin, W, att_s, att_d, xsb, a_src, a_dst);
}

// ---- K1b: one block per bucket (1563 = 6/CU) -> ELL csr + cnt ----
__global__ __launch_bounds__(256) void build_kernel(
    const int* __restrict__ gcnt, const int2* __restrict__ gbuf,
    int* __restrict__ cnt, unsigned* __restrict__ csr) {
  __shared__ int lc[BNODE];
  int t = threadIdx.x;
  int b = blockIdx.x;
  if (t < BNODE) lc[t] = 0;
  __syncthreads();
  int len = gcnt[b]; if (len > BCAP) len = BCAP;
  const int2* buf = gbuf + (size_t)b * BCAP;
  for (int i = t; i < len; i += 256) {
    int2 v = buf[i];
    int dl = (v.x >> 16) & 31;
    int s = v.x & 0xffff;
    int pos = atomicAdd(&lc[dl], 1);
    if (pos < SLOTS) {
      unsigned eb = ((unsigned)v.y) & 0xffff0000u;
      csr[(size_t)(b * BNODE + dl) * SLOTS + pos] = eb | (unsigned)s;
    }
  }
  __syncthreads();
  if (t < BNODE) {
    int n = b * BNODE + t;
    if (n < NN) cnt[n] = min(lc[t], SLOTS);
  }
}

// ---- K3: one wave per node (r13 dataflow). HEAD=false: res fp32, emits h1b
// (bf16) only. HEAD=true: res bf16 (h1b), emits scalar out.
template <bool HEAD>
__global__ __launch_bounds__(256) void aggregate_kernel(
    const int* __restrict__ cnt, const unsigned* __restrict__ csr,
    const unsigned short* __restrict__ xsb, const float* __restrict__ a_src,
    const float* __restrict__ a_dst, const float* __restrict__ We,
    const float* __restrict__ att_e, const float* __restrict__ bias,
    const void* __restrict__ resv, const float* __restrict__ g,
    const float* __restrict__ beta, const float* __restrict__ Wout,
    const float* __restrict__ bout, float* __restrict__ out,
    unsigned short* __restrict__ out_b) {
  __shared__ __align__(16) uint2 rec[4][64][4];  // [wave][slot][head]
  int t = threadIdx.x;
  int lane = t & 63, wave = t >> 6;
  int n = blockIdx.x * 4 + wave;  // grid exact: 12500*4 == 50000
  int d2 = lane & 31;
  int hb = d2 >> 3;
  int half = lane >> 5;

  float sp = We[lane] * att_e[lane];
#pragma unroll
  for (int off = 8; off; off >>= 1) sp += __shfl_xor(sp, off, 16);
  sp *= L2E;
  float s0 = __shfl(sp, 0, 64), s1 = __shfl(sp, 16, 64);
  float s2 = __shfl(sp, 32, 64), s3 = __shfl(sp, 48, 64);

  const float4 adv = *(const float4*)(a_dst + (size_t)n * 4);

  int dn = cnt[n];
  int r0 = n * SLOTS, r1 = r0 + dn;
  float accx = 0.f, accy = 0.f, den = 0.f, easum = 0.f;
  const uint2* rpb = &rec[wave][half][hb];
  const char* xd = (const char*)xsb + d2 * 4;

  for (int base = r0; base < r1; base += 64) {
    int c = r1 - base; if (c > 64) c = 64;
    int e = base + lane;
    unsigned ce = (e < r1) ? csr[e] : 0u;
    float ea = __uint_as_float(ce & 0xffff0000u);
    easum += ea;
    unsigned soff = (ce & 0xffffu) * 128u;
    float ex0 = 0.f, ex1 = 0.f, ex2 = 0.f, ex3 = 0.f;
    if (e < r1) {
      const float4 av = *(const float4*)(a_src + (size_t)(ce & 0xffffu) * 4);
      float a0 = av.x + fmaf(ea, s0, adv.x); a0 = fmaxf(a0, NEG * a0);
      float a1 = av.y + fmaf(ea, s1, adv.y); a1 = fmaxf(a1, NEG * a1);
      float a2 = av.z + fmaf(ea, s2, adv.z); a2 = fmaxf(a2, NEG * a2);
      float a3 = av.w + fmaf(ea, s3, adv.w); a3 = fmaxf(a3, NEG * a3);
      ex0 = exp2f(a0); ex1 = exp2f(a1); ex2 = exp2f(a2); ex3 = exp2f(a3);
    }
    uint4* wp = (uint4*)&rec[wave][lane][0];
    wp[0] = make_uint4(soff, __float_as_uint(ex0), soff, __float_as_uint(ex1));
    wp[1] = make_uint4(soff, __float_as_uint(ex2), soff, __float_as_uint(ex3));
    // phase B: 8 slots (8 edges) per step; pad slots have ex=0 -> no-op
    int c8 = (c + 7) & ~7;
    for (int j = 0; j < c8; j += 8) {
      uint2 va = rpb[j * 4];       // slot j+half
      uint2 vb = rpb[j * 4 + 8];   // slot j+2+half
      uint2 vc = rpb[j * 4 + 16];  // slot j+4+half
      uint2 vd = rpb[j * 4 + 24];  // slot j+6+half
      unsigned ua = *(const unsigned*)(xd + va.x);
      unsigned ub = *(const unsigned*)(xd + vb.x);
      unsigned uc = *(const unsigned*)(xd + vc.x);
      unsigned ud = *(const unsigned*)(xd + vd.x);
      float efa = __uint_as_float(va.y), efb = __uint_as_float(vb.y);
      float efc = __uint_as_float(vc.y), efd = __uint_as_float(vd.y);
      den += (efa + efb) + (efc + efd);
      accx = fmaf(efa, __uint_as_float(ua << 16), accx);
      accy = fmaf(efa, __uint_as_float(ua & 0xffff0000u), accy);
      accx = fmaf(efb, __uint_as_float(ub << 16), accx);
      accy = fmaf(efb, __uint_as_float(ub & 0xffff0000u), accy);
      accx = fmaf(efc, __uint_as_float(uc << 16), accx);
      accy = fmaf(efc, __uint_as_float(uc & 0xffff0000u), accy);
      accx = fmaf(efd, __uint_as_float(ud << 16), accx);
      accy = fmaf(efd, __uint_as_float(ud & 0xffff0000u), accy);
    }
  }

  den += __shfl_xor(den, 32, 64);
  accx += __shfl_xor(accx, 32, 64);
  accy += __shfl_xor(accy, 32, 64);
#pragma unroll
  for (int off = 32; off; off >>= 1) easum += __shfl_xor(easum, off, 64);

  float loop_ea = easum / fmaxf((float)dn, 1.0f);
  float as_h = a_src[(size_t)n * 4 + hb];
  float adn = (hb == 0) ? adv.x : (hb == 1) ? adv.y : (hb == 2) ? adv.z : adv.w;
  float sph = (hb == 0) ? s0 : (hb == 1) ? s1 : (hb == 2) ? s2 : s3;
  float a_self = as_h + fmaf(loop_ea, sph, adn);
  a_self = fmaxf(a_self, NEG * a_self);
  float ex_self = exp2f(a_self);
  den += ex_self;
  unsigned un = *(const unsigned*)((const char*)xsb + (size_t)n * 128 + d2 * 4);
  accx = fmaf(ex_self, __uint_as_float(un << 16), accx);
  accy = fmaf(ex_self, __uint_as_float(un & 0xffff0000u), accy);

  float rden = 1.f / (den + 1e-16f);
  const float2 bi = *(const float2*)(bias + d2 * 2);
  float2 rsd;
  if (HEAD) {  // residual from bf16 h1b
    unsigned ur =
        *(const unsigned*)((const unsigned short*)resv + (size_t)n * 64 + d2 * 2);
    rsd.x = bf16bits_to_f(ur & 0xffffu);
    rsd.y = __uint_as_float(ur & 0xffff0000u);
  } else {
    rsd = *(const float2*)((const float*)resv + (size_t)n * 64 + d2 * 2);
  }
  float vx = accx * rden + bi.x + rsd.x;
  float vy = accy * rden + bi.y + rsd.y;
  float s = vx + vy;
#pragma unroll
  for (int off = 32; off; off >>= 1) s += __shfl_xor(s, off, 64);
  float mu = s * (1.0f / 128.0f);
  float dx = vx - mu, dy = vy - mu;
  float var = dx * dx + dy * dy;
#pragma unroll
  for (int off = 32; off; off >>= 1) var += __shfl_xor(var, off, 64);
  var *= (1.0f / 128.0f);
  float rstd = rsqrtf(var + 1e-5f);
  const float2 gg = *(const float2*)(g + d2 * 2);
  const float2 bb = *(const float2*)(beta + d2 * 2);
  float yx = dx * rstd * gg.x + bb.x;
  float yy = dy * rstd * gg.y + bb.y;
  yx = yx > 0.f ? yx : expm1f(yx);
  yy = yy > 0.f ? yy : expm1f(yy);
  if (HEAD) {
    const float2 wv = *(const float2*)(Wout + d2 * 2);
    float p = yx * wv.x + yy * wv.y;
#pragma unroll
    for (int off = 32; off; off >>= 1) p += __shfl_xor(p, off, 64);
    if (lane == 0) out[n] = p * 0.5f + bout[0];
  } else if (lane < 32) {
    unsigned ob = f_to_bf16bits(yx) | (f_to_bf16bits(yy) << 16);
    *(unsigned*)(out_b + (size_t)n * 64 + d2 * 2) = ob;
  }
}

extern "C" void kernel_launch(void* const* d_in, const int* in_sizes, int n_in,
                              void* d_out, int out_size, void* d_ws,
                              size_t ws_size, hipStream_t stream) {
  const float* node_features = (const float*)d_in[0];
  const int* edge_index = (const int*)d_in[1];
  const int* src = edge_index;
  const int* dst = edge_index + NE;
  const float* edge_attr = (const float*)d_in[3];
  const float* W1 = (const float*)d_in[4];
  const float* att_src1 = (const float*)d_in[5];
  const float* att_dst1 = (const float*)d_in[6];
  const float* We1 = (const float*)d_in[7];
  const float* att_e1 = (const float*)d_in[8];
  const float* b1 = (const float*)d_in[9];
  const float* W2 = (const float*)d_in[10];
  const float* att_src2 = (const float*)d_in[11];
  const float* att_dst2 = (const float*)d_in[12];
  const float* We2 = (const float*)d_in[13];
  const float* att_e2 = (const float*)d_in[14];
  const float* b2 = (const float*)d_in[15];
  const float* g1 = (const float*)d_in[16];
  const float* beta1 = (const float*)d_in[17];
  const float* g2 = (const float*)d_in[18];
  const float* beta2 = (const float*)d_in[19];
  const float* Wout = (const float*)d_in[20];
  const float* bout = (const float*)d_in[21];
  float* out = (float*)d_out;

  char* ws = (char*)d_ws;
  size_t o = 0;
  auto alloc = [&](size_t bytes) {
    void* p = ws + o;
    o += (bytes + 255) & ~(size_t)255;
    return p;
  };
  int* gcnt = (int*)alloc((size_t)NBKT * 4);
  int2* gbuf = (int2*)alloc((size_t)NBKT * BCAP * 8);
  int* cnt = (int*)alloc((size_t)NN * 4);
  unsigned* csr = (unsigned*)alloc((size_t)NN * SLOTS * 4);
  unsigned short* xsb = (unsigned short*)alloc((size_t)NN * 64 * 2);
  unsigned short* h1b = (unsigned short*)alloc((size_t)NN * 64 * 2);
  float* a_srcb = (float*)alloc((size_t)NN * 4 * 4);
  float* a_dstb = (float*)alloc((size_t)NN * 4 * 4);

  hipMemsetAsync(gcnt, 0, (size_t)NBKT * 4, stream);

  // fused [bin | layer-1 GEMM]
  front_kernel<<<P1_BLOCKS + GEMM_BLOCKS, 256, 0, stream>>>(
      src, dst, edge_attr, gcnt, gbuf, node_features, W1, att_src1, att_dst1,
      xsb, a_srcb, a_dstb);
  build_kernel<<<NBKT, 256, 0, stream>>>(gcnt, gbuf, cnt, csr);

  // layer 1 aggregate -> h1b (bf16)
  aggregate_kernel<false><<<NN / 4, 256, 0, stream>>>(
      cnt, csr, xsb, a_srcb, a_dstb, We1, att_e1, b1, node_features, g1, beta1,
      nullptr, nullptr, nullptr, h1b);

  // layer 2
  gemm2_kernel<<<GEMM_BLOCKS, 256, 0, stream>>>(h1b, W2, att_src2, att_dst2,
                                                xsb, a_srcb, a_dstb);
  aggregate_kernel<true><<<NN / 4, 256, 0, stream>>>(
      cnt, csr, xsb, a_srcb, a_dstb, We2, att_e2, b2, h1b, g2, beta2, Wout,
      bout, out, nullptr);
}